// Round 3
// baseline (1880.347 us; speedup 1.0000x reference)
//
#include <hip/hip_runtime.h>
#include <hip/hip_bf16.h>

#define NVOX 200000
#define NK   125
#define GRID_LIN (128 * 128 * 128)
#define ASTRIDE 68                      // accum row stride (f32): pad 64->68 vs bank alias

// workspace layout (bytes)
#define WT_OFF    0u                    // 125*64*64*2      = 1,024,000
#define STATS_OFF 1024000u              // 128*4            = 512
#define PFX_OFF   1024512u              // 2048*4           = 8,192
#define OLD_OFF   1032704u              // 200,000*4        = 800,000
#define FB_OFF    1832704u              // (N+1)*128        = 25,600,128  (128B aligned)
#define IDX_OFF   27432832u             // 2M*4             = 8,388,608   -> ends 35,821,440

#define F16N   (NVOX * 16)              // 3,200,000
#define WCONV_N (NK * 4096)             // 512,000
#define PREP_N (F16N + 16 + WCONV_N)    // 3,712,016

typedef short bf16x8 __attribute__((ext_vector_type(8)));
typedef float f32x4  __attribute__((ext_vector_type(4)));
typedef unsigned short u16x4 __attribute__((ext_vector_type(4)));

static __device__ __forceinline__ unsigned short f2bf(float f) {
    union { float f; unsigned int u; } v; v.f = f;
    unsigned int u = v.u;
    return (unsigned short)((u + 0x7FFFu + ((u >> 16) & 1u)) >> 16);   // RNE
}

// K1: scatter original voxel id into idx_map (pre-memset to -1)
__global__ __launch_bounds__(256) void scatter_kernel(const int* __restrict__ coords,
                                                      int* __restrict__ idx_map) {
    int p = blockIdx.x * 256 + threadIdx.x;
    if (p < NVOX) {
        int z = coords[p * 3 + 0], y = coords[p * 3 + 1], x = coords[p * 3 + 2];
        idx_map[(z << 14) | (y << 7) | x] = p;
    }
}

// K2: per-1024-cell occupancy count
__global__ __launch_bounds__(1024) void count_kernel(const int* __restrict__ idx_map,
                                                     int* __restrict__ pfx) {
    __shared__ int wsum[16];
    int i = blockIdx.x * 1024 + threadIdx.x;
    int bit = idx_map[i] >= 0 ? 1 : 0;
    unsigned long long m = __ballot(bit);
    int lane = threadIdx.x & 63, wave = threadIdx.x >> 6;
    if (lane == 0) wsum[wave] = __popcll(m);
    __syncthreads();
    if (threadIdx.x == 0) {
        int s = 0;
#pragma unroll
        for (int w = 0; w < 16; ++w) s += wsum[w];
        pfx[blockIdx.x] = s;
    }
}

// K3: exclusive scan of 2048 block counts, single block
__global__ __launch_bounds__(1024) void scan_kernel(int* __restrict__ pfx) {
    __shared__ int A[2048], B[2048];
    int t = threadIdx.x;
    A[t] = pfx[t]; A[t + 1024] = pfx[t + 1024];
    __syncthreads();
    int* src = A; int* dst = B;
    for (int off = 1; off < 2048; off <<= 1) {
        dst[t]        = src[t]        + (t >= off ? src[t - off] : 0);
        dst[t + 1024] = src[t + 1024] + src[t + 1024 - off];
        __syncthreads();
        int* tmp = src; src = dst; dst = tmp;
    }
    pfx[t]        = t ? src[t - 1] : 0;
    pfx[t + 1024] = src[t + 1023];
}

// K4: relabel cells in spatial order; idx_map[cell] <- new id; oldof[new] = old id
__global__ __launch_bounds__(1024) void relabel_kernel(const int* __restrict__ pfx,
                                                       int* __restrict__ idx_map,
                                                       int* __restrict__ oldof) {
    __shared__ int wsum[16];
    int i = blockIdx.x * 1024 + threadIdx.x;
    int old = idx_map[i];
    int bit = old >= 0 ? 1 : 0;
    unsigned long long m = __ballot(bit);
    int lane = threadIdx.x & 63, wave = threadIdx.x >> 6;
    int intra = __popcll(m & ((1ull << lane) - 1ull));
    if (lane == 0) wsum[wave] = __popcll(m);
    __syncthreads();
    int woff = 0;
    for (int w = 0; w < wave; ++w) woff += wsum[w];
    if (bit) {
        int nid = pfx[blockIdx.x] + woff + intra;
        idx_map[i] = nid;
        oldof[nid] = old;
    }
}

// K5: fused prep — feats permuted f32->bf16 (+zero row at index NVOX); W
// [125][ci][co] f32 -> PLAIN [125][co][ci] bf16 (A-frags now read from global).
__global__ __launch_bounds__(256) void prep_kernel(const float* __restrict__ Wt,
                                                   const float* __restrict__ feats,
                                                   const int* __restrict__ oldof,
                                                   unsigned short* __restrict__ wt,
                                                   unsigned short* __restrict__ fb) {
    int i = blockIdx.x * 256 + threadIdx.x;
    if (i < F16N) {
        int p = i >> 4, c = i & 15;
        int old = oldof[p];
        f32x4 f = *(const f32x4*)(feats + (size_t)old * 64 + c * 4);
        u16x4 u;
        u[0] = f2bf(f[0]); u[1] = f2bf(f[1]); u[2] = f2bf(f[2]); u[3] = f2bf(f[3]);
        *(u16x4*)(fb + (size_t)i * 4) = u;
    } else if (i < F16N + 16) {
        *(u16x4*)(fb + (size_t)i * 4) = (u16x4)0;
    } else if (i < PREP_N) {
        int j = i - (F16N + 16);
        int k = j >> 12, r = j & 4095;
        int co = r >> 6, ci = r & 63;
        wt[(k << 12) + (co << 6) + ci] = f2bf(Wt[(k << 12) + (ci << 6) + co]);
    }
}

// Pair-compacted implicit-GEMM conv. Block = 256 consecutive (spatial) out
// voxels, XCD-swizzled. The grid is uniform-random ~9.76% occupied, so a dense
// 16-voxel MFMA tile holds only ~1.6 hit columns -> the old dense kernel wasted
// ~87% of its MFMA/gather work on zeros. Here, per k (125): each thread probes
// its 1 neighbor cell; hits are ballot-compacted into an LDS pair list
// (in_id<<9 | out_slot); pairs are processed in 16-pair MFMA tiles (pad = zero
// feature row -> exact +0). A = W_k read straight from global (L1/L2-hot; no
// W LDS, no staging barriers). Output accumulates in a padded f32 LDS image
// via ds_add atomics; one scatter + BN-stat pass at block end.
__global__ __launch_bounds__(256, 2) void conv_kernel(
    const int* __restrict__ coords, const unsigned short* __restrict__ fb,
    const unsigned short* __restrict__ wt, const int* __restrict__ idx_map,
    const int* __restrict__ oldof,
    float* __restrict__ out, float* __restrict__ stats) {
    __shared__ float accum[256 * ASTRIDE];        // 69,632 B
    __shared__ unsigned int plist[256];           // 1 KB pair list (per k)
    __shared__ int pcnt2[2];                      // dbuf counters (iter parity)

    const int vblk = (blockIdx.x & 7) * 98 + (blockIdx.x >> 3);
    const int vbase = vblk * 256;
    if (vbase >= NVOX) return;

    const int tid  = threadIdx.x;
    const int wave = tid >> 6;
    const int lane = tid & 63;
    const int g    = lane >> 4;
    const int l15  = lane & 15;
    const int vox  = vbase + tid;
    const bool live = vox < NVOX;
    const int rot  = vblk % 25;                   // per-block k-phase offset

    int z = 0, y = 0, x = 0;
    if (live) {
        int old = oldof[vox];
        z = coords[old * 3 + 0]; y = coords[old * 3 + 1]; x = coords[old * 3 + 2];
    }

    // zero accum (256*68 f32 = 4352 f32x4, 17 per thread) + counters
    {
        f32x4* az = (f32x4*)accum;
#pragma unroll
        for (int i = 0; i < 17; ++i) az[i * 256 + tid] = (f32x4)0.0f;
        if (tid < 2) pcnt2[tid] = 0;
    }
    __syncthreads();

    const char* fbp = (const char*)fb;
    const char* wtp = (const char*)wt;

    for (int grp = 0; grp < 25; ++grp) {
        int ge = grp + rot; if (ge >= 25) ge -= 25;
        const int dz = ge / 5 - 2, dy = ge % 5 - 2;
        const int nz = z + dz, ny = y + dy;
        const bool rowok = live && ((unsigned)nz < 128u) && ((unsigned)ny < 128u);
        const int base = (nz << 14) | (ny << 7);
#pragma unroll 1
        for (int kk = 0; kk < 5; ++kk) {
            const int k  = ge * 5 + kk;
            const int it = grp * 5 + kk;          // iteration parity for counter dbuf
            // ---- probe + compact ----
            int j = -1;
            int nx = x + kk - 2;
            if (rowok && ((unsigned)nx < 128u)) j = idx_map[base | nx];
            unsigned long long m = __ballot(j >= 0);
            int intra = __popcll(m & ((1ull << lane) - 1ull));
            int wcnt  = __popcll(m);
            int wbase = 0;
            if (lane == 0 && wcnt) wbase = atomicAdd(&pcnt2[it & 1], wcnt);
            wbase = __shfl(wbase, 0, 64);
            if (j >= 0) plist[wbase + intra] = ((unsigned)j << 9) | (unsigned)tid;
            __syncthreads();                      // list + count visible

            const int cnt = pcnt2[it & 1];
            const int nt  = (cnt + 15) >> 4;
            // ---- 16-pair MFMA tiles, waves strided ----
            for (int t = wave; t < nt; t += 4) {
                int pi = t * 16 + l15;
                unsigned e = (pi < cnt) ? plist[pi] : ((unsigned)NVOX << 9);
                int pj   = (int)(e >> 9);
                int slot = (int)(e & 511u);
                const char* rp = fbp + ((size_t)(unsigned)pj << 7) + (g << 4);
                bf16x8 b0 = *(const bf16x8*)(rp);
                bf16x8 b1 = *(const bf16x8*)(rp + 64);
                const char* wb = wtp + ((size_t)k << 13) + (l15 << 7) + (g << 4);
                f32x4 c[4];
#pragma unroll
                for (int a = 0; a < 4; ++a) {
                    bf16x8 a0 = *(const bf16x8*)(wb + a * 2048);
                    bf16x8 a1 = *(const bf16x8*)(wb + a * 2048 + 64);
                    c[a] = (f32x4)0.0f;
                    c[a] = __builtin_amdgcn_mfma_f32_16x16x32_bf16(a0, b0, c[a], 0, 0, 0);
                    c[a] = __builtin_amdgcn_mfma_f32_16x16x32_bf16(a1, b1, c[a], 0, 0, 0);
                }
                // scatter: lane's column = pair l15 -> accum row `slot`
                float* arow = &accum[slot * ASTRIDE];
#pragma unroll
                for (int a = 0; a < 4; ++a)
#pragma unroll
                    for (int r = 0; r < 4; ++r)
                        atomicAdd(&arow[a * 16 + g * 4 + r], c[a][r]);
            }
            __syncthreads();                      // tiles done before list reuse
            if (tid == 0) pcnt2[it & 1] = 0;      // safe: next use is it+2,
        }                                         // fenced by it+1's barriers
    }

    // ---- BN batch-stat partials: lane c sums channel c over wave's 64 rows ----
    {
        float s = 0.f, q = 0.f;
        for (int i = 0; i < 64; ++i) {
            float v = accum[(wave * 64 + i) * ASTRIDE + lane];
            s += v; q += v * v;
        }
        atomicAdd(&stats[lane], s);
        atomicAdd(&stats[64 + lane], q);
    }

    // ---- scatter rows back to ORIGINAL voxel order (bias cancels under BN) ----
    if (live) {
        int o = oldof[vox];
        const float* arow = &accum[tid * ASTRIDE];
#pragma unroll
        for (int a2 = 0; a2 < 16; ++a2)
            *(f32x4*)(out + (size_t)o * 64 + a2 * 4) = *(const f32x4*)(arow + a2 * 4);
    }
}

__global__ __launch_bounds__(256) void finalize_kernel(float* __restrict__ out,
                                                       const float* __restrict__ stats,
                                                       const float* __restrict__ gamma,
                                                       const float* __restrict__ beta) {
    int i = blockIdx.x * 256 + threadIdx.x;
    if (i >= NVOX * 16) return;
    int cg = (i & 15) * 4;
    f32x4 v = *(f32x4*)(out + (size_t)i * 4);
    f32x4 r;
#pragma unroll
    for (int c = 0; c < 4; ++c) {
        int co = cg + c;
        float mean = stats[co] * (1.0f / NVOX);
        float var  = stats[64 + co] * (1.0f / NVOX) - mean * mean;
        float sc   = rsqrtf(var + 1e-5f) * gamma[co];
        float sh   = beta[co] - mean * sc;
        float yv   = v[c] * sc + sh;
        r[c] = yv > 0.f ? yv : expm1f(yv);
    }
    *(f32x4*)(out + (size_t)i * 4) = r;
}

extern "C" void kernel_launch(void* const* d_in, const int* in_sizes, int n_in,
                              void* d_out, int out_size, void* d_ws, size_t ws_size,
                              hipStream_t stream) {
    const float* feats  = (const float*)d_in[0];
    const int*   coords = (const int*)d_in[1];
    const float* Wt     = (const float*)d_in[2];
    // d_in[3] = bias: unused — cancels exactly under training-mode BN
    const float* gamma  = (const float*)d_in[4];
    const float* beta   = (const float*)d_in[5];
    float* out = (float*)d_out;
    char*  ws  = (char*)d_ws;

    unsigned short* wt  = (unsigned short*)(ws + WT_OFF);
    float* stats        = (float*)(ws + STATS_OFF);
    int*   pfx          = (int*)(ws + PFX_OFF);
    int*   oldof        = (int*)(ws + OLD_OFF);
    unsigned short* fb  = (unsigned short*)(ws + FB_OFF);
    int*   idx_map      = (int*)(ws + IDX_OFF);

    hipMemsetAsync(idx_map, 0xFF, (size_t)GRID_LIN * 4, stream);  // -1
    hipMemsetAsync(stats, 0, 128 * 4, stream);

    scatter_kernel<<<(NVOX + 255) / 256, 256, 0, stream>>>(coords, idx_map);
    count_kernel<<<GRID_LIN / 1024, 1024, 0, stream>>>(idx_map, pfx);
    scan_kernel<<<1, 1024, 0, stream>>>(pfx);
    relabel_kernel<<<GRID_LIN / 1024, 1024, 0, stream>>>(pfx, idx_map, oldof);
    prep_kernel<<<(PREP_N + 255) / 256, 256, 0, stream>>>(Wt, feats, oldof, wt, fb);
    conv_kernel<<<784, 256, 0, stream>>>(coords, fb, wt, idx_map, oldof, out, stats);
    finalize_kernel<<<12500, 256, 0, stream>>>(out, stats, gamma, beta);
}

// Round 4
// 1329.612 us; speedup vs baseline: 1.4142x; 1.4142x over previous
//
#include <hip/hip_runtime.h>
#include <hip/hip_bf16.h>

#define NVOX 200000
#define NK   125
#define GRID_LIN (128 * 128 * 128)
#define ASTRIDE 67                      // accum row stride (f32): odd -> ~2-way LDS banks

// workspace layout (bytes)
#define WT_OFF    0u                    // 125*64*64*2      = 1,024,000
#define STATS_OFF 1024000u              // 128*4            = 512
#define PFX_OFF   1024512u              // 2048*4           = 8,192
#define OLD_OFF   1032704u              // 200,000*4        = 800,000
#define FB_OFF    1832704u              // (N+1)*128        = 25,600,128  (128B aligned)
#define IDX_OFF   27432832u             // 2M*4             = 8,388,608   -> ends 35,821,440

#define F16N   (NVOX * 16)              // 3,200,000
#define WCONV_N (NK * 4096)             // 512,000
#define PREP_N (F16N + 16 + WCONV_N)    // 3,712,016

typedef short bf16x8 __attribute__((ext_vector_type(8)));
typedef float f32x4  __attribute__((ext_vector_type(4)));
typedef unsigned short u16x4 __attribute__((ext_vector_type(4)));

static __device__ __forceinline__ unsigned short f2bf(float f) {
    union { float f; unsigned int u; } v; v.f = f;
    unsigned int u = v.u;
    return (unsigned short)((u + 0x7FFFu + ((u >> 16) & 1u)) >> 16);   // RNE
}

// K1: scatter original voxel id into idx_map (pre-memset to -1)
__global__ __launch_bounds__(256) void scatter_kernel(const int* __restrict__ coords,
                                                      int* __restrict__ idx_map) {
    int p = blockIdx.x * 256 + threadIdx.x;
    if (p < NVOX) {
        int z = coords[p * 3 + 0], y = coords[p * 3 + 1], x = coords[p * 3 + 2];
        idx_map[(z << 14) | (y << 7) | x] = p;
    }
}

// K2: per-1024-cell occupancy count
__global__ __launch_bounds__(1024) void count_kernel(const int* __restrict__ idx_map,
                                                     int* __restrict__ pfx) {
    __shared__ int wsum[16];
    int i = blockIdx.x * 1024 + threadIdx.x;
    int bit = idx_map[i] >= 0 ? 1 : 0;
    unsigned long long m = __ballot(bit);
    int lane = threadIdx.x & 63, wave = threadIdx.x >> 6;
    if (lane == 0) wsum[wave] = __popcll(m);
    __syncthreads();
    if (threadIdx.x == 0) {
        int s = 0;
#pragma unroll
        for (int w = 0; w < 16; ++w) s += wsum[w];
        pfx[blockIdx.x] = s;
    }
}

// K3: exclusive scan of 2048 block counts, single block
__global__ __launch_bounds__(1024) void scan_kernel(int* __restrict__ pfx) {
    __shared__ int A[2048], B[2048];
    int t = threadIdx.x;
    A[t] = pfx[t]; A[t + 1024] = pfx[t + 1024];
    __syncthreads();
    int* src = A; int* dst = B;
    for (int off = 1; off < 2048; off <<= 1) {
        dst[t]        = src[t]        + (t >= off ? src[t - off] : 0);
        dst[t + 1024] = src[t + 1024] + src[t + 1024 - off];
        __syncthreads();
        int* tmp = src; src = dst; dst = tmp;
    }
    pfx[t]        = t ? src[t - 1] : 0;
    pfx[t + 1024] = src[t + 1023];
}

// K4: relabel cells in spatial order; idx_map[cell] <- new id; oldof[new] = old id
__global__ __launch_bounds__(1024) void relabel_kernel(const int* __restrict__ pfx,
                                                       int* __restrict__ idx_map,
                                                       int* __restrict__ oldof) {
    __shared__ int wsum[16];
    int i = blockIdx.x * 1024 + threadIdx.x;
    int old = idx_map[i];
    int bit = old >= 0 ? 1 : 0;
    unsigned long long m = __ballot(bit);
    int lane = threadIdx.x & 63, wave = threadIdx.x >> 6;
    int intra = __popcll(m & ((1ull << lane) - 1ull));
    if (lane == 0) wsum[wave] = __popcll(m);
    __syncthreads();
    int woff = 0;
    for (int w = 0; w < wave; ++w) woff += wsum[w];
    if (bit) {
        int nid = pfx[blockIdx.x] + woff + intra;
        idx_map[i] = nid;
        oldof[nid] = old;
    }
}

// K5: fused prep — feats permuted f32->bf16 (+zero row at index NVOX); W
// [125][ci][co] f32 -> PLAIN [125][co][ci] bf16 (A-frags read from global/L2).
__global__ __launch_bounds__(256) void prep_kernel(const float* __restrict__ Wt,
                                                   const float* __restrict__ feats,
                                                   const int* __restrict__ oldof,
                                                   unsigned short* __restrict__ wt,
                                                   unsigned short* __restrict__ fb) {
    int i = blockIdx.x * 256 + threadIdx.x;
    if (i < F16N) {
        int p = i >> 4, c = i & 15;
        int old = oldof[p];
        f32x4 f = *(const f32x4*)(feats + (size_t)old * 64 + c * 4);
        u16x4 u;
        u[0] = f2bf(f[0]); u[1] = f2bf(f[1]); u[2] = f2bf(f[2]); u[3] = f2bf(f[3]);
        *(u16x4*)(fb + (size_t)i * 4) = u;
    } else if (i < F16N + 16) {
        *(u16x4*)(fb + (size_t)i * 4) = (u16x4)0;
    } else if (i < PREP_N) {
        int j = i - (F16N + 16);
        int k = j >> 12, r = j & 4095;
        int co = r >> 6, ci = r & 63;
        wt[(k << 12) + (co << 6) + ci] = f2bf(Wt[(k << 12) + (ci << 6) + co]);
    }
}

// Pair-compacted conv, GROUP-granular phases (fixes round-3's 250 tiny barrier
// phases). Block = 256 consecutive spatial outputs, XCD-swizzled + k-rotated.
// Per (dz,dy) group (25 total): probe 5 dx cells (issued BEFORE the barrier ->
// latency hides under barrier wait), ballot-append hits into 5 per-k pair lists
// (parity-dbuf'd lists+counters; resets happen one phase ahead, never racing),
// ONE barrier, then a flat queue of ~10 16-pair MFMA tiles split in contiguous
// chunks across the 4 waves, reusing W A-frags in registers across same-k
// tiles. Pad pairs use the zero feature row (exact +0). Output accumulates in
// a 256x67 f32 LDS image (odd stride ~2-way banks) via ds_add atomics; BN
// stats + scatter once at block end. 2 barriers/group = 50 total, with ~8.3x
// less MFMA+gather work than the dense kernel (grid is 9.76% occupied).
__global__ __launch_bounds__(256, 2) void conv_kernel(
    const int* __restrict__ coords, const unsigned short* __restrict__ fb,
    const unsigned short* __restrict__ wt, const int* __restrict__ idx_map,
    const int* __restrict__ oldof,
    float* __restrict__ out, float* __restrict__ stats) {
    __shared__ float accum[256 * ASTRIDE];        // 68,608 B
    __shared__ unsigned int plist[2][5 * 256];    // 10,240 B (parity dbuf)
    __shared__ int pcnt[2][8];                    // 64 B    (parity dbuf)

    const int vblk = (blockIdx.x & 7) * 98 + (blockIdx.x >> 3);
    const int vbase = vblk * 256;
    if (vbase >= NVOX) return;

    const int tid  = threadIdx.x;
    const int wave = tid >> 6;
    const int lane = tid & 63;
    const int g    = lane >> 4;
    const int l15  = lane & 15;
    const int vox  = vbase + tid;
    const bool live = vox < NVOX;
    const int rot  = vblk % 25;                   // per-block k-phase offset

    int z = 0, y = 0, x = 0;
    if (live) {
        int old = oldof[vox];
        z = coords[old * 3 + 0]; y = coords[old * 3 + 1]; x = coords[old * 3 + 2];
    }

    // zero accum (256*67 f32 = 4288 f32x4) + both counter banks
    {
        f32x4* az = (f32x4*)accum;
#pragma unroll
        for (int i = 0; i < 16; ++i) az[i * 256 + tid] = (f32x4)0.0f;
        if (tid < 192) az[4096 + tid] = (f32x4)0.0f;
        if (tid < 16) ((int*)pcnt)[tid] = 0;
    }
    __syncthreads();

    const char* fbp = (const char*)fb;
    const char* wtp = (const char*)wt;

    for (int grp = 0; grp < 25; ++grp) {
        int ge = grp + rot; if (ge >= 25) ge -= 25;
        const int par = grp & 1;
        const int dz = ge / 5 - 2, dy = ge % 5 - 2;
        const int nz = z + dz, ny = y + dy;
        const bool rowok = live && ((unsigned)nz < 128u) && ((unsigned)ny < 128u);
        const int base = (nz << 14) | (ny << 7);

        // ---- probe 5 cells (issued pre-barrier; latency hides under B0) ----
        int jj[5];
#pragma unroll
        for (int kk = 0; kk < 5; ++kk) {
            int nx = x + kk - 2;
            jj[kk] = (rowok && ((unsigned)nx < 128u)) ? idx_map[base | nx] : -1;
        }

        __syncthreads();   // B0: prev tile phase done; pcnt[par] reset visible

        // ---- append hits to per-k lists ----
#pragma unroll
        for (int kk = 0; kk < 5; ++kk) {
            int j = jj[kk];
            unsigned long long m = __ballot(j >= 0);
            int wcnt = __popcll(m);
            if (wcnt) {
                int intra = __popcll(m & ((1ull << lane) - 1ull));
                int wbase = 0;
                if (lane == 0) wbase = atomicAdd(&pcnt[par][kk], wcnt);
                wbase = __shfl(wbase, 0, 64);
                if (j >= 0)
                    plist[par][kk * 256 + wbase + intra] = ((unsigned)j << 8) | (unsigned)tid;
            }
        }

        __syncthreads();   // B1: lists + counts visible
        if (tid < 8) pcnt[1 - par][tid] = 0;      // reset for NEXT group (its
                                                  // appends are fenced by its B0)
        // ---- flat tile queue: contiguous chunks per wave, af reuse per k ----
        int cnts[5], pref[6]; pref[0] = 0;
#pragma unroll
        for (int kk = 0; kk < 5; ++kk) {
            cnts[kk] = pcnt[par][kk];
            pref[kk + 1] = pref[kk] + ((cnts[kk] + 15) >> 4);
        }
        const int tot = pref[5];
        const int chunk = (tot + 3) >> 2;
        const int q0 = wave * chunk;
        const int q1 = (q0 + chunk < tot) ? q0 + chunk : tot;

        int kkp = -1;
        bf16x8 af0[4], af1[4];
#pragma unroll 1
        for (int q = q0; q < q1; ++q) {
            int kk = 0;
#pragma unroll
            for (int s = 1; s < 5; ++s) if (q >= pref[s]) kk = s;
            const int t = q - pref[kk];
            const int pi = t * 16 + l15;
            const bool vld = pi < cnts[kk];
            unsigned e = vld ? plist[par][kk * 256 + pi] : ((unsigned)NVOX << 8);
            const int pj   = (int)(e >> 8);
            const int slot = (int)(e & 255u);

            const char* rp = fbp + ((size_t)(unsigned)pj << 7) + (g << 4);
            bf16x8 b0 = *(const bf16x8*)(rp);
            bf16x8 b1 = *(const bf16x8*)(rp + 64);

            if (kk != kkp) {                      // wave-uniform W reload
                const int k = ge * 5 + kk;
                const char* wb = wtp + ((size_t)k << 13) + (l15 << 7) + (g << 4);
#pragma unroll
                for (int a = 0; a < 4; ++a) {
                    af0[a] = *(const bf16x8*)(wb + a * 2048);
                    af1[a] = *(const bf16x8*)(wb + a * 2048 + 64);
                }
                kkp = kk;
            }

            f32x4 c[4];
#pragma unroll
            for (int a = 0; a < 4; ++a) {
                c[a] = (f32x4)0.0f;
                c[a] = __builtin_amdgcn_mfma_f32_16x16x32_bf16(af0[a], b0, c[a], 0, 0, 0);
                c[a] = __builtin_amdgcn_mfma_f32_16x16x32_bf16(af1[a], b1, c[a], 0, 0, 0);
            }
            if (vld) {
                float* arow = &accum[slot * ASTRIDE];
#pragma unroll
                for (int a = 0; a < 4; ++a)
#pragma unroll
                    for (int r = 0; r < 4; ++r)
                        atomicAdd(&arow[a * 16 + g * 4 + r], c[a][r]);
            }
        }
    }
    __syncthreads();

    // ---- BN batch-stat partials: lane c sums channel c over wave's 64 rows ----
    {
        float s = 0.f, q2 = 0.f;
        for (int i = 0; i < 64; ++i) {
            float v = accum[(wave * 64 + i) * ASTRIDE + lane];
            s += v; q2 += v * v;
        }
        atomicAdd(&stats[lane], s);
        atomicAdd(&stats[64 + lane], q2);
    }

    // ---- scatter rows back to ORIGINAL voxel order (bias cancels under BN) ----
    if (live) {
        int o = oldof[vox];
        const float* arow = &accum[tid * ASTRIDE];
#pragma unroll
        for (int a2 = 0; a2 < 16; ++a2) {
            f32x4 v;
            v[0] = arow[a2 * 4 + 0]; v[1] = arow[a2 * 4 + 1];
            v[2] = arow[a2 * 4 + 2]; v[3] = arow[a2 * 4 + 3];
            *(f32x4*)(out + (size_t)o * 64 + a2 * 4) = v;
        }
    }
}

__global__ __launch_bounds__(256) void finalize_kernel(float* __restrict__ out,
                                                       const float* __restrict__ stats,
                                                       const float* __restrict__ gamma,
                                                       const float* __restrict__ beta) {
    int i = blockIdx.x * 256 + threadIdx.x;
    if (i >= NVOX * 16) return;
    int cg = (i & 15) * 4;
    f32x4 v = *(f32x4*)(out + (size_t)i * 4);
    f32x4 r;
#pragma unroll
    for (int c = 0; c < 4; ++c) {
        int co = cg + c;
        float mean = stats[co] * (1.0f / NVOX);
        float var  = stats[64 + co] * (1.0f / NVOX) - mean * mean;
        float sc   = rsqrtf(var + 1e-5f) * gamma[co];
        float sh   = beta[co] - mean * sc;
        float yv   = v[c] * sc + sh;
        r[c] = yv > 0.f ? yv : expm1f(yv);
    }
    *(f32x4*)(out + (size_t)i * 4) = r;
}

extern "C" void kernel_launch(void* const* d_in, const int* in_sizes, int n_in,
                              void* d_out, int out_size, void* d_ws, size_t ws_size,
                              hipStream_t stream) {
    const float* feats  = (const float*)d_in[0];
    const int*   coords = (const int*)d_in[1];
    const float* Wt     = (const float*)d_in[2];
    // d_in[3] = bias: unused — cancels exactly under training-mode BN
    const float* gamma  = (const float*)d_in[4];
    const float* beta   = (const float*)d_in[5];
    float* out = (float*)d_out;
    char*  ws  = (char*)d_ws;

    unsigned short* wt  = (unsigned short*)(ws + WT_OFF);
    float* stats        = (float*)(ws + STATS_OFF);
    int*   pfx          = (int*)(ws + PFX_OFF);
    int*   oldof        = (int*)(ws + OLD_OFF);
    unsigned short* fb  = (unsigned short*)(ws + FB_OFF);
    int*   idx_map      = (int*)(ws + IDX_OFF);

    hipMemsetAsync(idx_map, 0xFF, (size_t)GRID_LIN * 4, stream);  // -1
    hipMemsetAsync(stats, 0, 128 * 4, stream);

    scatter_kernel<<<(NVOX + 255) / 256, 256, 0, stream>>>(coords, idx_map);
    count_kernel<<<GRID_LIN / 1024, 1024, 0, stream>>>(idx_map, pfx);
    scan_kernel<<<1, 1024, 0, stream>>>(pfx);
    relabel_kernel<<<GRID_LIN / 1024, 1024, 0, stream>>>(pfx, idx_map, oldof);
    prep_kernel<<<(PREP_N + 255) / 256, 256, 0, stream>>>(Wt, feats, oldof, wt, fb);
    conv_kernel<<<784, 256, 0, stream>>>(coords, fb, wt, idx_map, oldof, out, stats);
    finalize_kernel<<<12500, 256, 0, stream>>>(out, stats, gamma, beta);
}

// Round 5
// 1124.811 us; speedup vs baseline: 1.6717x; 1.1821x over previous
//
#include <hip/hip_runtime.h>
#include <hip/hip_bf16.h>

#define NVOX 200000
#define NK   125
#define GRID_LIN (128 * 128 * 128)

// workspace layout (bytes)
#define WT_OFF    0u                    // 125*64*64*2      = 1,024,000
#define STATS_OFF 1024000u              // 128*4            = 512
#define PFX_OFF   1024512u              // 2048*4           = 8,192
#define OLD_OFF   1032704u              // 200,000*4        = 800,000
#define FB_OFF    1832704u              // (N+1)*128        = 25,600,128  (128B aligned)
#define IDX_OFF   27432832u             // 2M*4             = 8,388,608   -> ends 35,821,440

#define F16N   (NVOX * 16)              // 3,200,000
#define WCONV_N (NK * 4096)             // 512,000
#define PREP_N (F16N + 16 + WCONV_N)    // 3,712,016

typedef short bf16x8 __attribute__((ext_vector_type(8)));
typedef float f32x4  __attribute__((ext_vector_type(4)));
typedef unsigned short u16x4 __attribute__((ext_vector_type(4)));

static __device__ __forceinline__ unsigned short f2bf(float f) {
    union { float f; unsigned int u; } v; v.f = f;
    unsigned int u = v.u;
    return (unsigned short)((u + 0x7FFFu + ((u >> 16) & 1u)) >> 16);   // RNE
}

// K1: scatter original voxel id into idx_map (pre-memset to -1)
__global__ __launch_bounds__(256) void scatter_kernel(const int* __restrict__ coords,
                                                      int* __restrict__ idx_map) {
    int p = blockIdx.x * 256 + threadIdx.x;
    if (p < NVOX) {
        int z = coords[p * 3 + 0], y = coords[p * 3 + 1], x = coords[p * 3 + 2];
        idx_map[(z << 14) | (y << 7) | x] = p;
    }
}

// K2: per-1024-cell occupancy count
__global__ __launch_bounds__(1024) void count_kernel(const int* __restrict__ idx_map,
                                                     int* __restrict__ pfx) {
    __shared__ int wsum[16];
    int i = blockIdx.x * 1024 + threadIdx.x;
    int bit = idx_map[i] >= 0 ? 1 : 0;
    unsigned long long m = __ballot(bit);
    int lane = threadIdx.x & 63, wave = threadIdx.x >> 6;
    if (lane == 0) wsum[wave] = __popcll(m);
    __syncthreads();
    if (threadIdx.x == 0) {
        int s = 0;
#pragma unroll
        for (int w = 0; w < 16; ++w) s += wsum[w];
        pfx[blockIdx.x] = s;
    }
}

// K3: exclusive scan of 2048 block counts, single block
__global__ __launch_bounds__(1024) void scan_kernel(int* __restrict__ pfx) {
    __shared__ int A[2048], B[2048];
    int t = threadIdx.x;
    A[t] = pfx[t]; A[t + 1024] = pfx[t + 1024];
    __syncthreads();
    int* src = A; int* dst = B;
    for (int off = 1; off < 2048; off <<= 1) {
        dst[t]        = src[t]        + (t >= off ? src[t - off] : 0);
        dst[t + 1024] = src[t + 1024] + src[t + 1024 - off];
        __syncthreads();
        int* tmp = src; src = dst; dst = tmp;
    }
    pfx[t]        = t ? src[t - 1] : 0;
    pfx[t + 1024] = src[t + 1023];
}

// K4: relabel cells in spatial order; idx_map[cell] <- new id; oldof[new] = old id
__global__ __launch_bounds__(1024) void relabel_kernel(const int* __restrict__ pfx,
                                                       int* __restrict__ idx_map,
                                                       int* __restrict__ oldof) {
    __shared__ int wsum[16];
    int i = blockIdx.x * 1024 + threadIdx.x;
    int old = idx_map[i];
    int bit = old >= 0 ? 1 : 0;
    unsigned long long m = __ballot(bit);
    int lane = threadIdx.x & 63, wave = threadIdx.x >> 6;
    int intra = __popcll(m & ((1ull << lane) - 1ull));
    if (lane == 0) wsum[wave] = __popcll(m);
    __syncthreads();
    int woff = 0;
    for (int w = 0; w < wave; ++w) woff += wsum[w];
    if (bit) {
        int nid = pfx[blockIdx.x] + woff + intra;
        idx_map[i] = nid;
        oldof[nid] = old;
    }
}

// K5: fused prep — feats permuted f32->bf16 (+zero row at index NVOX); W
// [125][ci][co] f32 -> PLAIN [125][co][ci] bf16 (A-frags read from global/L1/L2).
__global__ __launch_bounds__(256) void prep_kernel(const float* __restrict__ Wt,
                                                   const float* __restrict__ feats,
                                                   const int* __restrict__ oldof,
                                                   unsigned short* __restrict__ wt,
                                                   unsigned short* __restrict__ fb) {
    int i = blockIdx.x * 256 + threadIdx.x;
    if (i < F16N) {
        int p = i >> 4, c = i & 15;
        int old = oldof[p];
        f32x4 f = *(const f32x4*)(feats + (size_t)old * 64 + c * 4);
        u16x4 u;
        u[0] = f2bf(f[0]); u[1] = f2bf(f[1]); u[2] = f2bf(f[2]); u[3] = f2bf(f[3]);
        *(u16x4*)(fb + (size_t)i * 4) = u;
    } else if (i < F16N + 16) {
        *(u16x4*)(fb + (size_t)i * 4) = (u16x4)0;
    } else if (i < PREP_N) {
        int j = i - (F16N + 16);
        int k = j >> 12, r = j & 4095;
        int co = r >> 6, ci = r & 63;
        wt[(k << 12) + (co << 6) + ci] = f2bf(Wt[(k << 12) + (ci << 6) + co]);
    }
}

// Barrier-free dense conv. Block = 256 consecutive spatial out voxels (XCD-
// swizzled slab -> fb window ~3.2MB = XCD-L2-resident). ZERO LDS: W A-frags
// read straight from global (1MB, identical across waves -> L1/L2-hot), the
// per-tile neighbor transpose done with __shfl (bpermute) instead of an LDS
// roundtrip. Result: no __syncthreads anywhere in the k-loop -> no vmcnt(0)
// drains, no phase-locking; occupancy is register-bound (~3 waves/SIMD vs 2
// blocks/CU before). Per-wave software pipeline over flat k=0..124, unroll x2
// (static dbuf indices): probes 3-deep, B-gathers 1-deep (bbA/bbB), A-frags
// streamed per a (L1-hot, 2 MFMAs each). Dead probes read the zero feature
// row (exact +0). Per-t __any zero-tile skip (~19%).
#define PROBE(kk, dst) do {                                                  \
    int k_ = (kk);                                                           \
    dst = -1;                                                                \
    if (k_ < NK) {                                                           \
        int dz_ = (k_ * 41) >> 10; int r_ = k_ - dz_ * 25;                   \
        int dy_ = (r_ * 205) >> 10; int dx_ = r_ - dy_ * 5;                  \
        int nz_ = z + dz_ - 2, ny_ = y + dy_ - 2, nx_ = x + dx_ - 2;         \
        if (live && ((unsigned)nz_ < 128u) && ((unsigned)ny_ < 128u)         \
                 && ((unsigned)nx_ < 128u))                                  \
            dst = idx_map[(nz_ << 14) | (ny_ << 7) | nx_];                   \
    }                                                                        \
} while (0)

#define GATHER(jsrc, jt, bb) do {                                            \
    _Pragma("unroll")                                                        \
    for (int t_ = 0; t_ < 4; ++t_) {                                         \
        int jv_ = __shfl(jsrc, t_ * 16 + l15, 64);                           \
        jt[t_] = (jv_ < 0) ? NVOX : jv_;                                     \
        const char* rp_ = fbp + ((size_t)(unsigned)jt[t_] << 7) + (g << 4);  \
        bb[t_ * 2]     = *(const bf16x8*)(rp_);                              \
        bb[t_ * 2 + 1] = *(const bf16x8*)(rp_ + 64);                         \
    }                                                                        \
} while (0)

#define COMPUTE(k_, jt, bb) do {                                             \
    const char* wb_ = wtp + ((size_t)(k_) << 13) + (l15 << 7) + (g << 4);    \
    bool kt_[4];                                                             \
    _Pragma("unroll")                                                        \
    for (int t_ = 0; t_ < 4; ++t_) kt_[t_] = __any(jt[t_] != NVOX);          \
    _Pragma("unroll")                                                        \
    for (int a_ = 0; a_ < 4; ++a_) {                                         \
        bf16x8 a0_ = *(const bf16x8*)(wb_ + a_ * 2048);                      \
        bf16x8 a1_ = *(const bf16x8*)(wb_ + a_ * 2048 + 64);                 \
        _Pragma("unroll")                                                    \
        for (int t_ = 0; t_ < 4; ++t_) {                                     \
            if (kt_[t_]) {                                                   \
                acc[a_][t_] = __builtin_amdgcn_mfma_f32_16x16x32_bf16(       \
                    a0_, bb[t_ * 2], acc[a_][t_], 0, 0, 0);                  \
                acc[a_][t_] = __builtin_amdgcn_mfma_f32_16x16x32_bf16(       \
                    a1_, bb[t_ * 2 + 1], acc[a_][t_], 0, 0, 0);              \
            }                                                                \
        }                                                                    \
    }                                                                        \
} while (0)

__global__ __launch_bounds__(256, 3) void conv_kernel(
    const int* __restrict__ coords, const unsigned short* __restrict__ fb,
    const unsigned short* __restrict__ wt, const int* __restrict__ idx_map,
    const int* __restrict__ oldof,
    float* __restrict__ out, float* __restrict__ stats) {

    const int vblk = (blockIdx.x & 7) * 98 + (blockIdx.x >> 3);
    const int vbase = vblk * 256;
    if (vbase >= NVOX) return;

    const int tid  = threadIdx.x;
    const int wave = tid >> 6;
    const int lane = tid & 63;
    const int g    = lane >> 4;
    const int l15  = lane & 15;
    const int vox  = vbase + tid;
    const bool live = vox < NVOX;

    int z = 0, y = 0, x = 0;
    if (live) {
        int old = oldof[vox];
        z = coords[old * 3 + 0]; y = coords[old * 3 + 1]; x = coords[old * 3 + 2];
    }

    f32x4 acc[4][4];
#pragma unroll
    for (int a = 0; a < 4; ++a)
#pragma unroll
        for (int b = 0; b < 4; ++b) acc[a][b] = (f32x4)0.0f;

    const char* fbp = (const char*)fb;
    const char* wtp = (const char*)wt;

    // ---- software-pipelined k-loop: probes 3-deep, gathers 1-deep ----
    int jtA[4], jtB[4];
    bf16x8 bbA[8], bbB[8];
    int j0, jB, jC, jD, jE;

    PROBE(0, j0); PROBE(1, jB); PROBE(2, jC);
    GATHER(j0, jtA, bbA);                         // k=0 (one-time exposed wait)

#pragma unroll 1
    for (int k = 0; k < 124; k += 2) {
        // entering: bbA = gathers(k), jB = probe(k+1) [arrived], jC = probe(k+2)
        PROBE(k + 3, jD);
        GATHER(jB, jtB, bbB);                     // k+1
        __builtin_amdgcn_sched_barrier(0);
        COMPUTE(k, jtA, bbA);

        PROBE(k + 4, jE);
        GATHER(jC, jtA, bbA);                     // k+2
        __builtin_amdgcn_sched_barrier(0);
        COMPUTE(k + 1, jtB, bbB);

        jB = jD; jC = jE;
    }
    COMPUTE(124, jtA, bbA);                       // tail (125 odd)

    // epilogue: scatter rows back to ORIGINAL voxel order (bias cancels under BN)
#pragma unroll
    for (int b = 0; b < 4; ++b) {
        int v = vbase + wave * 64 + b * 16 + l15;
        if (v < NVOX) {
            int o = oldof[v];
#pragma unroll
            for (int a = 0; a < 4; ++a)
                *(f32x4*)(out + (size_t)o * 64 + a * 16 + g * 4) = acc[a][b];
        }
    }

    // BN batch-stat partials over this wave's 64 voxels
    float s1[16], s2[16];
#pragma unroll
    for (int a = 0; a < 4; ++a)
#pragma unroll
        for (int r = 0; r < 4; ++r) {
            float s = 0.f, q = 0.f;
#pragma unroll
            for (int b = 0; b < 4; ++b) { float xv = acc[a][b][r]; s += xv; q += xv * xv; }
            s1[a * 4 + r] = s; s2[a * 4 + r] = q;
        }
#pragma unroll
    for (int m = 1; m < 16; m <<= 1) {
#pragma unroll
        for (int i = 0; i < 16; ++i) {
            s1[i] += __shfl_xor(s1[i], m, 64);
            s2[i] += __shfl_xor(s2[i], m, 64);
        }
    }
    if (l15 == 0) {
#pragma unroll
        for (int a = 0; a < 4; ++a)
#pragma unroll
            for (int r = 0; r < 4; ++r) {
                int co = a * 16 + g * 4 + r;
                atomicAdd(&stats[co],      s1[a * 4 + r]);
                atomicAdd(&stats[64 + co], s2[a * 4 + r]);
            }
    }
}

__global__ __launch_bounds__(256) void finalize_kernel(float* __restrict__ out,
                                                       const float* __restrict__ stats,
                                                       const float* __restrict__ gamma,
                                                       const float* __restrict__ beta) {
    int i = blockIdx.x * 256 + threadIdx.x;
    if (i >= NVOX * 16) return;
    int cg = (i & 15) * 4;
    f32x4 v = *(f32x4*)(out + (size_t)i * 4);
    f32x4 r;
#pragma unroll
    for (int c = 0; c < 4; ++c) {
        int co = cg + c;
        float mean = stats[co] * (1.0f / NVOX);
        float var  = stats[64 + co] * (1.0f / NVOX) - mean * mean;
        float sc   = rsqrtf(var + 1e-5f) * gamma[co];
        float sh   = beta[co] - mean * sc;
        float yv   = v[c] * sc + sh;
        r[c] = yv > 0.f ? yv : expm1f(yv);
    }
    *(f32x4*)(out + (size_t)i * 4) = r;
}

extern "C" void kernel_launch(void* const* d_in, const int* in_sizes, int n_in,
                              void* d_out, int out_size, void* d_ws, size_t ws_size,
                              hipStream_t stream) {
    const float* feats  = (const float*)d_in[0];
    const int*   coords = (const int*)d_in[1];
    const float* Wt     = (const float*)d_in[2];
    // d_in[3] = bias: unused — cancels exactly under training-mode BN
    const float* gamma  = (const float*)d_in[4];
    const float* beta   = (const float*)d_in[5];
    float* out = (float*)d_out;
    char*  ws  = (char*)d_ws;

    unsigned short* wt  = (unsigned short*)(ws + WT_OFF);
    float* stats        = (float*)(ws + STATS_OFF);
    int*   pfx          = (int*)(ws + PFX_OFF);
    int*   oldof        = (int*)(ws + OLD_OFF);
    unsigned short* fb  = (unsigned short*)(ws + FB_OFF);
    int*   idx_map      = (int*)(ws + IDX_OFF);

    hipMemsetAsync(idx_map, 0xFF, (size_t)GRID_LIN * 4, stream);  // -1
    hipMemsetAsync(stats, 0, 128 * 4, stream);

    scatter_kernel<<<(NVOX + 255) / 256, 256, 0, stream>>>(coords, idx_map);
    count_kernel<<<GRID_LIN / 1024, 1024, 0, stream>>>(idx_map, pfx);
    scan_kernel<<<1, 1024, 0, stream>>>(pfx);
    relabel_kernel<<<GRID_LIN / 1024, 1024, 0, stream>>>(pfx, idx_map, oldof);
    prep_kernel<<<(PREP_N + 255) / 256, 256, 0, stream>>>(Wt, feats, oldof, wt, fb);
    conv_kernel<<<784, 256, 0, stream>>>(coords, fb, wt, idx_map, oldof, out, stats);
    finalize_kernel<<<12500, 256, 0, stream>>>(out, stats, gamma, beta);
}

// Round 6
// 680.587 us; speedup vs baseline: 2.7628x; 1.6527x over previous
//
#include <hip/hip_runtime.h>
#include <hip/hip_bf16.h>

#define NVOX 200000
#define NK   125
#define GRID_LIN (128 * 128 * 128)

// workspace layout (bytes)
#define WT_OFF    0u                    // 125*64*64*2      = 1,024,000
#define STATS_OFF 1024000u              // 128*4            = 512
#define PFX_OFF   1024512u              // 2048*4           = 8,192
#define OLD_OFF   1032704u              // 200,000*4        = 800,000
#define FB_OFF    1832704u              // (N+1)*128        = 25,600,128  (128B aligned)
#define IDX_OFF   27432832u             // 2M*4             = 8,388,608   -> ends 35,821,440

#define F16N   (NVOX * 16)              // 3,200,000
#define WCONV_N (NK * 4096)             // 512,000
#define PREP_N (F16N + 16 + WCONV_N)    // 3,712,016

typedef short bf16x8 __attribute__((ext_vector_type(8)));
typedef float f32x4  __attribute__((ext_vector_type(4)));
typedef unsigned short u16x4 __attribute__((ext_vector_type(4)));
typedef unsigned int uint_as1 __attribute__((address_space(1)));
typedef unsigned int uint_as3 __attribute__((address_space(3)));

static __device__ __forceinline__ unsigned short f2bf(float f) {
    union { float f; unsigned int u; } v; v.f = f;
    unsigned int u = v.u;
    return (unsigned short)((u + 0x7FFFu + ((u >> 16) & 1u)) >> 16);   // RNE
}

// K1: scatter original voxel id into idx_map (pre-memset to -1)
__global__ __launch_bounds__(256) void scatter_kernel(const int* __restrict__ coords,
                                                      int* __restrict__ idx_map) {
    int p = blockIdx.x * 256 + threadIdx.x;
    if (p < NVOX) {
        int z = coords[p * 3 + 0], y = coords[p * 3 + 1], x = coords[p * 3 + 2];
        idx_map[(z << 14) | (y << 7) | x] = p;
    }
}

// K2: per-1024-cell occupancy count
__global__ __launch_bounds__(1024) void count_kernel(const int* __restrict__ idx_map,
                                                     int* __restrict__ pfx) {
    __shared__ int wsum[16];
    int i = blockIdx.x * 1024 + threadIdx.x;
    int bit = idx_map[i] >= 0 ? 1 : 0;
    unsigned long long m = __ballot(bit);
    int lane = threadIdx.x & 63, wave = threadIdx.x >> 6;
    if (lane == 0) wsum[wave] = __popcll(m);
    __syncthreads();
    if (threadIdx.x == 0) {
        int s = 0;
#pragma unroll
        for (int w = 0; w < 16; ++w) s += wsum[w];
        pfx[blockIdx.x] = s;
    }
}

// K3: exclusive scan of 2048 block counts, single block
__global__ __launch_bounds__(1024) void scan_kernel(int* __restrict__ pfx) {
    __shared__ int A[2048], B[2048];
    int t = threadIdx.x;
    A[t] = pfx[t]; A[t + 1024] = pfx[t + 1024];
    __syncthreads();
    int* src = A; int* dst = B;
    for (int off = 1; off < 2048; off <<= 1) {
        dst[t]        = src[t]        + (t >= off ? src[t - off] : 0);
        dst[t + 1024] = src[t + 1024] + src[t + 1024 - off];
        __syncthreads();
        int* tmp = src; src = dst; dst = tmp;
    }
    pfx[t]        = t ? src[t - 1] : 0;
    pfx[t + 1024] = src[t + 1023];
}

// K4: relabel cells in spatial order; idx_map[cell] <- new id; oldof[new] = old id
__global__ __launch_bounds__(1024) void relabel_kernel(const int* __restrict__ pfx,
                                                       int* __restrict__ idx_map,
                                                       int* __restrict__ oldof) {
    __shared__ int wsum[16];
    int i = blockIdx.x * 1024 + threadIdx.x;
    int old = idx_map[i];
    int bit = old >= 0 ? 1 : 0;
    unsigned long long m = __ballot(bit);
    int lane = threadIdx.x & 63, wave = threadIdx.x >> 6;
    int intra = __popcll(m & ((1ull << lane) - 1ull));
    if (lane == 0) wsum[wave] = __popcll(m);
    __syncthreads();
    int woff = 0;
    for (int w = 0; w < wave; ++w) woff += wsum[w];
    if (bit) {
        int nid = pfx[blockIdx.x] + woff + intra;
        idx_map[i] = nid;
        oldof[nid] = old;
    }
}

// K5: fused prep — feats permuted f32->bf16 (+zero row at index NVOX); W
// [125][ci][co] f32 -> lane-coalesced A-frag layout: ushort index within slice
// r = (a*2+half)*512 + lane*8 + e  holds W[co = a*16+(lane&15)]
//                                       [ci = half*32 + (lane>>4)*8 + e]
// so conv's af load = one contiguous 1KB global_load_dwordx4 per (a,half).
__global__ __launch_bounds__(256) void prep_kernel(const float* __restrict__ Wt,
                                                   const float* __restrict__ feats,
                                                   const int* __restrict__ oldof,
                                                   unsigned short* __restrict__ wt,
                                                   unsigned short* __restrict__ fb) {
    int i = blockIdx.x * 256 + threadIdx.x;
    if (i < F16N) {
        int p = i >> 4, c = i & 15;
        int old = oldof[p];
        f32x4 f = *(const f32x4*)(feats + (size_t)old * 64 + c * 4);
        u16x4 u;
        u[0] = f2bf(f[0]); u[1] = f2bf(f[1]); u[2] = f2bf(f[2]); u[3] = f2bf(f[3]);
        *(u16x4*)(fb + (size_t)i * 4) = u;
    } else if (i < F16N + 16) {
        *(u16x4*)(fb + (size_t)i * 4) = (u16x4)0;
    } else if (i < PREP_N) {
        int j = i - (F16N + 16);
        int k = j >> 12, r = j & 4095;
        int a2h = r >> 9;                 // a*2+half
        int ln  = (r >> 3) & 63;
        int e   = r & 7;
        int co  = (a2h >> 1) * 16 + (ln & 15);
        int ci  = (a2h & 1) * 32 + ((ln >> 4) << 3) + e;
        wt[(k << 12) + r] = f2bf(Wt[(k << 12) + (ci << 6) + co]);
    }
}

// Conv with LDS-pipelined B-gathers (the round-2/5 lesson: the compiler will
// NOT keep multi-kk register double-buffers alive — VGPR_Count pinned at 84 —
// so the pipeline must live in LDS, not VGPRs). Block = 256 consecutive
// spatial out voxels, XCD-swizzled + k-rotated. Per wave: two private 8KB
// B-slots in LDS; per kk, 8 global_load_lds (per-lane global src = the legal
// scatter side; LDS dst = linear lane*16B) stage the NEXT kk's 4 16-voxel
// feature tiles while this kk's tiles are ds_read from the other slot.
// Hand-placed `s_waitcnt vmcnt(8)` (counted — next slot's 8 loads stay in
// flight) + sched_barrier fences, m201-style. Bank conflicts on the b128
// reads killed by XOR-swizzling the SOURCE chunk (c^(r&7), involution) and
// reading with the same XOR. W read per-kk from global (L1/L2-hot; 1KB
// coalesced per instruction via the prep layout); one barrier per (dz,dy)
// group keeps the 4 waves' W windows L1-coherent. Probes batched per group,
// per-k __ballot masks give the ~19% zero-tile MFMA skip.
#define PROBEG(ge_, jj_) do {                                                \
    int dz_ = (ge_) / 5 - 2, dy_ = (ge_) % 5 - 2;                            \
    int nz_ = z + dz_, ny_ = y + dy_;                                        \
    bool rok_ = live && ((unsigned)nz_ < 128u) && ((unsigned)ny_ < 128u);    \
    int base_ = (nz_ << 14) | (ny_ << 7);                                    \
    _Pragma("unroll")                                                        \
    for (int kk_ = 0; kk_ < 5; ++kk_) {                                      \
        int nx_ = x + kk_ - 2;                                               \
        jj_[kk_] = (rok_ && ((unsigned)nx_ < 128u)) ? idx_map[base_ | nx_]   \
                                                    : -1;                    \
    }                                                                        \
} while (0)

#define STAGE(j5v, slot_) do {                                               \
    unsigned short* dst_ = &lds_b[wave][slot_][lane * 8];                    \
    _Pragma("unroll")                                                        \
    for (int i_ = 0; i_ < 8; ++i_) {                                         \
        int jv_ = __shfl((j5v), i_ * 8 + (lane >> 3), 64);                   \
        const char* src_ = fbp + ((size_t)(unsigned)jv_ << 7) + coff;        \
        __builtin_amdgcn_global_load_lds((const uint_as1*)(const void*)src_, \
            (uint_as3*)(void*)(dst_ + i_ * 512), 16, 0, 0);                  \
    }                                                                        \
} while (0)

#define KK(kk_, slot_) do {                                                  \
    asm volatile("s_waitcnt vmcnt(8)" ::: "memory");                         \
    __builtin_amdgcn_sched_barrier(0);                                       \
    const char* bs_ = bwave + (slot_) * 8192;                                \
    bf16x8 b0_[4], b1_[4];                                                   \
    _Pragma("unroll")                                                        \
    for (int t_ = 0; t_ < 4; ++t_) {                                         \
        b0_[t_] = *(const bf16x8*)(bs_ + t_ * 2048 + sw0);                   \
        b1_[t_] = *(const bf16x8*)(bs_ + t_ * 2048 + sw1);                   \
    }                                                                        \
    __builtin_amdgcn_sched_barrier(0);                                       \
    const char* wk_ = wk + (size_t)(kk_) * 8192;                             \
    bf16x8 af0_[4], af1_[4];                                                 \
    _Pragma("unroll")                                                        \
    for (int a_ = 0; a_ < 4; ++a_) {                                         \
        af0_[a_] = *(const bf16x8*)(wk_ + a_ * 2048);                        \
        af1_[a_] = *(const bf16x8*)(wk_ + a_ * 2048 + 1024);                 \
    }                                                                        \
    if ((kk_) + 2 < 5) STAGE(j5[(kk_) + 2], (kk_) & 1);                      \
    _Pragma("unroll")                                                        \
    for (int t_ = 0; t_ < 4; ++t_) {                                         \
        if ((unsigned)((mk[kk_] >> (t_ * 16)) & 0xFFFFull)) {                \
            _Pragma("unroll")                                                \
            for (int a_ = 0; a_ < 4; ++a_) {                                 \
                acc[a_][t_] = __builtin_amdgcn_mfma_f32_16x16x32_bf16(       \
                    af0_[a_], b0_[t_], acc[a_][t_], 0, 0, 0);                \
                acc[a_][t_] = __builtin_amdgcn_mfma_f32_16x16x32_bf16(       \
                    af1_[a_], b1_[t_], acc[a_][t_], 0, 0, 0);                \
            }                                                                \
        }                                                                    \
    }                                                                        \
} while (0)

__global__ __launch_bounds__(256, 2) void conv_kernel(
    const int* __restrict__ coords, const unsigned short* __restrict__ fb,
    const unsigned short* __restrict__ wt, const int* __restrict__ idx_map,
    const int* __restrict__ oldof,
    float* __restrict__ out, float* __restrict__ stats) {
    __shared__ unsigned short lds_b[4][2][4096];   // 64 KB: [wave][slot][8KB]

    const int vblk = (blockIdx.x & 7) * 98 + (blockIdx.x >> 3);
    const int vbase = vblk * 256;
    if (vbase >= NVOX) return;

    const int tid  = threadIdx.x;
    const int wave = tid >> 6;
    const int lane = tid & 63;
    const int g    = lane >> 4;
    const int l15  = lane & 15;
    const int vox  = vbase + tid;
    const bool live = vox < NVOX;
    const int rot  = vblk % 25;                   // per-block k-phase offset

    int z = 0, y = 0, x = 0;
    if (live) {
        int old = oldof[vox];
        z = coords[old * 3 + 0]; y = coords[old * 3 + 1]; x = coords[old * 3 + 2];
    }

    // lane constants
    const int coff = (((lane & 7) ^ ((lane >> 3) & 7)) << 4);  // stage src swizzle
    const int sw0  = ((g    ) ^ (l15 & 7)) << 4;               // read swizzle, half 0
    const int sw1  = ((4 + g) ^ (l15 & 7)) << 4;               // read swizzle, half 1
    const char* bwave = (const char*)&lds_b[wave][0][0] + (l15 << 7);
    const char* fbp = (const char*)fb;
    const char* wtp = (const char*)wt + lane * 16;

    f32x4 acc[4][4];
#pragma unroll
    for (int a = 0; a < 4; ++a)
#pragma unroll
        for (int b = 0; b < 4; ++b) acc[a][b] = (f32x4)0.0f;

    // group-0 probe (results land in mk/j5 before the loop)
    int j5[5];
    unsigned long long mk[5];
    {
        int jj[5];
        PROBEG(rot, jj);
#pragma unroll
        for (int kk = 0; kk < 5; ++kk) {
            mk[kk] = __ballot(jj[kk] >= 0);
            j5[kk] = jj[kk] < 0 ? NVOX : jj[kk];
        }
    }

#pragma unroll 1
    for (int grp = 0; grp < 25; ++grp) {
        int ge = grp + rot; if (ge >= 25) ge -= 25;
        const char* wk = wtp + (size_t)(ge * 5) * 8192;

        STAGE(j5[0], 0);
        STAGE(j5[1], 1);

        // probe NEXT group early: ~5 kk of compute hides the gather latency
        int jn[5];
        if (grp < 24) {
            int ge2 = ge + 1; if (ge2 >= 25) ge2 -= 25;
            PROBEG(ge2, jn);
        }

        KK(0, 0); KK(1, 1); KK(2, 0); KK(3, 1); KK(4, 0);

        if (grp < 24) {
#pragma unroll
            for (int kk = 0; kk < 5; ++kk) {
                mk[kk] = __ballot(jn[kk] >= 0);
                j5[kk] = jn[kk] < 0 ? NVOX : jn[kk];
            }
        }
        __syncthreads();   // keep 4 waves' W windows L1-coherent (no data dep)
    }

    // epilogue: scatter rows back to ORIGINAL voxel order (bias cancels under BN)
#pragma unroll
    for (int b = 0; b < 4; ++b) {
        int v = vbase + wave * 64 + b * 16 + l15;
        if (v < NVOX) {
            int o = oldof[v];
#pragma unroll
            for (int a = 0; a < 4; ++a)
                *(f32x4*)(out + (size_t)o * 64 + a * 16 + g * 4) = acc[a][b];
        }
    }

    // BN batch-stat partials over this wave's 64 voxels
    float s1[16], s2[16];
#pragma unroll
    for (int a = 0; a < 4; ++a)
#pragma unroll
        for (int r = 0; r < 4; ++r) {
            float s = 0.f, q = 0.f;
#pragma unroll
            for (int b = 0; b < 4; ++b) { float xv = acc[a][b][r]; s += xv; q += xv * xv; }
            s1[a * 4 + r] = s; s2[a * 4 + r] = q;
        }
#pragma unroll
    for (int m = 1; m < 16; m <<= 1) {
#pragma unroll
        for (int i = 0; i < 16; ++i) {
            s1[i] += __shfl_xor(s1[i], m, 64);
            s2[i] += __shfl_xor(s2[i], m, 64);
        }
    }
    if (l15 == 0) {
#pragma unroll
        for (int a = 0; a < 4; ++a)
#pragma unroll
            for (int r = 0; r < 4; ++r) {
                int co = a * 16 + g * 4 + r;
                atomicAdd(&stats[co],      s1[a * 4 + r]);
                atomicAdd(&stats[64 + co], s2[a * 4 + r]);
            }
    }
}

__global__ __launch_bounds__(256) void finalize_kernel(float* __restrict__ out,
                                                       const float* __restrict__ stats,
                                                       const float* __restrict__ gamma,
                                                       const float* __restrict__ beta) {
    int i = blockIdx.x * 256 + threadIdx.x;
    if (i >= NVOX * 16) return;
    int cg = (i & 15) * 4;
    f32x4 v = *(f32x4*)(out + (size_t)i * 4);
    f32x4 r;
#pragma unroll
    for (int c = 0; c < 4; ++c) {
        int co = cg + c;
        float mean = stats[co] * (1.0f / NVOX);
        float var  = stats[64 + co] * (1.0f / NVOX) - mean * mean;
        float sc   = rsqrtf(var + 1e-5f) * gamma[co];
        float sh   = beta[co] - mean * sc;
        float yv   = v[c] * sc + sh;
        r[c] = yv > 0.f ? yv : expm1f(yv);
    }
    *(f32x4*)(out + (size_t)i * 4) = r;
}

extern "C" void kernel_launch(void* const* d_in, const int* in_sizes, int n_in,
                              void* d_out, int out_size, void* d_ws, size_t ws_size,
                              hipStream_t stream) {
    const float* feats  = (const float*)d_in[0];
    const int*   coords = (const int*)d_in[1];
    const float* Wt     = (const float*)d_in[2];
    // d_in[3] = bias: unused — cancels exactly under training-mode BN
    const float* gamma  = (const float*)d_in[4];
    const float* beta   = (const float*)d_in[5];
    float* out = (float*)d_out;
    char*  ws  = (char*)d_ws;

    unsigned short* wt  = (unsigned short*)(ws + WT_OFF);
    float* stats        = (float*)(ws + STATS_OFF);
    int*   pfx          = (int*)(ws + PFX_OFF);
    int*   oldof        = (int*)(ws + OLD_OFF);
    unsigned short* fb  = (unsigned short*)(ws + FB_OFF);
    int*   idx_map      = (int*)(ws + IDX_OFF);

    hipMemsetAsync(idx_map, 0xFF, (size_t)GRID_LIN * 4, stream);  // -1
    hipMemsetAsync(stats, 0, 128 * 4, stream);

    scatter_kernel<<<(NVOX + 255) / 256, 256, 0, stream>>>(coords, idx_map);
    count_kernel<<<GRID_LIN / 1024, 1024, 0, stream>>>(idx_map, pfx);
    scan_kernel<<<1, 1024, 0, stream>>>(pfx);
    relabel_kernel<<<GRID_LIN / 1024, 1024, 0, stream>>>(pfx, idx_map, oldof);
    prep_kernel<<<(PREP_N + 255) / 256, 256, 0, stream>>>(Wt, feats, oldof, wt, fb);
    conv_kernel<<<784, 256, 0, stream>>>(coords, fb, wt, idx_map, oldof, out, stats);
    finalize_kernel<<<12500, 256, 0, stream>>>(out, stats, gamma, beta);
}